// Round 2
// baseline (1048.579 us; speedup 1.0000x reference)
//
#include <hip/hip_runtime.h>

#define DIM   64
#define KCB   1024
#define NROWS 131072

// ws layout (floats): ws[0] = loss accumulator; ws[256 .. 256+1023] = csq[k]

// Precompute csq[k] = sum(cb[k]^2) mimicking numpy pairwise (8-acc) order,
// and zero the loss accumulator (ws is re-poisoned to 0xAA before every call).
__global__ void vq_prep(const float* __restrict__ cb, float* __restrict__ ws) {
    int k = blockIdx.x * blockDim.x + threadIdx.x;
    if (k < KCB) {
        const float* e = cb + (k << 6);
        {
            #pragma clang fp contract(off)
            float racc[8];
            #pragma unroll
            for (int j = 0; j < 8; ++j) racc[j] = e[j] * e[j];
            #pragma unroll
            for (int t = 1; t < 8; ++t) {
                #pragma unroll
                for (int j = 0; j < 8; ++j) racc[j] += e[8 * t + j] * e[8 * t + j];
            }
            ws[256 + k] = ((racc[0] + racc[1]) + (racc[2] + racc[3]))
                        + ((racc[4] + racc[5]) + (racc[6] + racc[7]));
        }
    }
    if (k == 0) ws[0] = 0.0f;
}

// Block = 256 threads: waves 0-1 scan k in [0,512) for rows r0..r0+127,
// waves 2-3 scan k in [512,1024) for the same rows. k is wave-uniform ->
// codebook loads scalarize (s_load broadcast). Halves combined in LDS with
// the sequential strict-< tie-break rule (equal -> lower k).
__global__ __launch_bounds__(256, 4) void vq_argmin(
        const float* __restrict__ in,
        const float* __restrict__ cb,
        const float* __restrict__ csq,      // = ws + 256
        float* __restrict__ codes_f,
        float* __restrict__ loss_acc)       // = ws + 0
{
    const int tid  = threadIdx.x;
    const int half = tid >> 7;              // wave-uniform (waves 0,1 -> 0; 2,3 -> 1)
    const int lr   = tid & 127;
    const int row  = blockIdx.x * 128 + lr;

    const float4* x4p = (const float4*)(in + (size_t)row * DIM);
    float x[64];
    #pragma unroll
    for (int i = 0; i < 16; ++i) {
        float4 v = x4p[i];
        x[4 * i + 0] = v.x; x[4 * i + 1] = v.y;
        x[4 * i + 2] = v.z; x[4 * i + 3] = v.w;
    }

    // A = ||x||^2, numpy pairwise 8-accumulator order, squares rounded separately
    float A;
    {
        #pragma clang fp contract(off)
        float racc[8];
        #pragma unroll
        for (int j = 0; j < 8; ++j) racc[j] = x[j] * x[j];
        #pragma unroll
        for (int t = 1; t < 8; ++t) {
            #pragma unroll
            for (int j = 0; j < 8; ++j) racc[j] += x[8 * t + j] * x[8 * t + j];
        }
        A = ((racc[0] + racc[1]) + (racc[2] + racc[3]))
          + ((racc[4] + racc[5]) + (racc[6] + racc[7]));
    }

    const int    kbase = half << 9;
    const float* cbp   = cb  + ((size_t)kbase << 6);
    const float* cs    = csq + kbase;

    float dmin = 3.402823466e38f;
    int   kmin = 0;

    #pragma unroll 1
    for (int kk = 0; kk < 512; kk += 2) {
        const float* e0 = cbp + (kk << 6);
        const float* e1 = e0 + 64;
        // Sequential fma chains (same accumulation order as the passing R1
        // kernel); two independent chains hide dependent-fma latency.
        float m0 = 0.0f, m1 = 0.0f;
        #pragma unroll
        for (int j = 0; j < 64; ++j) {
            m0 = __builtin_fmaf(x[j], e0[j], m0);
            m1 = __builtin_fmaf(x[j], e1[j], m1);
        }
        float d0, d1;
        {
            #pragma clang fp contract(off)
            d0 = (A - 2.0f * m0) + cs[kk];
            d1 = (A - 2.0f * m1) + cs[kk + 1];
        }
        if (d0 < dmin) { dmin = d0; kmin = kk; }
        if (d1 < dmin) { dmin = d1; kmin = kk + 1; }
    }

    __shared__ float ds[256];
    __shared__ int   ks[256];
    ds[tid] = dmin;
    ks[tid] = kmin;
    __syncthreads();

    float lsum = 0.0f;
    if (tid < 128) {
        float d0 = ds[tid], d1 = ds[tid + 128];
        int   k0 = ks[tid], k1 = ks[tid + 128] + 512;
        // full-scan equivalence: second half wins only on strict <
        int   code = (d1 < d0) ? k1 : k0;
        float db   = (d1 < d0) ? d1 : d0;
        codes_f[row] = (float)code;
        lsum = db;
    }
    __syncthreads();
    ds[tid] = lsum;                 // threads >=128 contribute 0
    __syncthreads();
    #pragma unroll
    for (int s = 128; s > 0; s >>= 1) {
        if (tid < s) ds[tid] += ds[tid + s];
        __syncthreads();
    }
    if (tid == 0) atomicAdd(loss_acc, ds[0]);
}

// Coalesced gather + straight-through write; lane 0 of the grid also
// finalizes the loss (argmin kernel has fully completed by stream order).
__global__ __launch_bounds__(256) void vq_quant(const float* __restrict__ in,
                                                const float* __restrict__ cb,
                                                const float* __restrict__ codes_f,
                                                float* __restrict__ out,
                                                const float* __restrict__ loss_acc,
                                                float* __restrict__ loss_out) {
    int t = blockIdx.x * 256 + threadIdx.x;   // one float4 per thread
    int row = t >> 4;                          // 16 threads per row
    int seg = t & 15;
    int code = (int)codes_f[row];
    const float4* q4 = (const float4*)(cb + ((size_t)code << 6));
    float4 xv = ((const float4*)in)[t];
    float4 qv = q4[seg];
    float4 st;
    {
        #pragma clang fp contract(off)
        st.x = xv.x + (qv.x - xv.x);
        st.y = xv.y + (qv.y - xv.y);
        st.z = xv.z + (qv.z - xv.z);
        st.w = xv.w + (qv.w - xv.w);
    }
    ((float4*)out)[t] = st;
    if (t == 0) {
        // loss = codebook_loss + BETA*commitment = 1.25 * mean((x-q)^2)
        loss_out[0] = 1.25f * loss_acc[0] / 8388608.0f;
    }
}

extern "C" void kernel_launch(void* const* d_in, const int* in_sizes, int n_in,
                              void* d_out, int out_size, void* d_ws, size_t ws_size,
                              hipStream_t stream) {
    const float* in = (const float*)d_in[0];   // (32,4096,64) fp32
    const float* cb = (const float*)d_in[1];   // (1024,64)    fp32
    float* out     = (float*)d_out;
    float* codes_f = out + 8388608;
    float* loss_p  = out + 8519680;
    float* ws      = (float*)d_ws;

    vq_prep  <<<4,    256, 0, stream>>>(cb, ws);
    vq_argmin<<<1024, 256, 0, stream>>>(in, cb, ws + 256, codes_f, ws);
    vq_quant <<<8192, 256, 0, stream>>>(in, cb, codes_f, out, ws, loss_p);
}

// Round 3
// 420.839 us; speedup vs baseline: 2.4916x; 2.4916x over previous
//
#include <hip/hip_runtime.h>

#define DIM   64
#define KCB   1024
#define NROWS 131072

// ws layout (floats): ws[0] = loss accumulator; ws[256 .. 256+1023] = csq[k]

// Precompute csq[k] = sum(cb[k]^2) mimicking numpy pairwise (8-acc) order,
// and zero the loss accumulator (ws is re-poisoned to 0xAA before every call).
__global__ void vq_prep(const float* __restrict__ cb, float* __restrict__ ws) {
    int k = blockIdx.x * blockDim.x + threadIdx.x;
    if (k < KCB) {
        const float* e = cb + (k << 6);
        {
            #pragma clang fp contract(off)
            float racc[8];
            #pragma unroll
            for (int j = 0; j < 8; ++j) racc[j] = e[j] * e[j];
            #pragma unroll
            for (int t = 1; t < 8; ++t) {
                #pragma unroll
                for (int j = 0; j < 8; ++j) racc[j] += e[8 * t + j] * e[8 * t + j];
            }
            ws[256 + k] = ((racc[0] + racc[1]) + (racc[2] + racc[3]))
                        + ((racc[4] + racc[5]) + (racc[6] + racc[7]));
        }
    }
    if (k == 0) ws[0] = 0.0f;
}

// Block = 256 threads: waves 0-1 scan k in [0,512) for rows r0..r0+127,
// waves 2-3 scan k in [512,1024) for the same rows.
//  - kbase forced into an SGPR via readfirstlane -> codebook loads scalarize
//    (s_load broadcast on the scalar pipe; R1's SGPR=112 pattern).
//  - x[64] pinned in VGPRs via opaque asm -> compiler cannot rematerialize
//    (R1/R2's 17 GB FETCH_SIZE was per-k re-loads of x from global).
//  - launch_bounds(256,4): VGPR budget 128 >= ~90 needed for resident x.
__global__ __launch_bounds__(256, 4) void vq_argmin(
        const float* __restrict__ in,
        const float* __restrict__ cb,
        const float* __restrict__ csq,      // = ws + 256
        float* __restrict__ codes_f,
        float* __restrict__ loss_acc)       // = ws + 0
{
    const int tid  = threadIdx.x;
    const int half = tid >> 7;              // wave-uniform (waves 0,1 -> 0; 2,3 -> 1)
    const int lr   = tid & 127;
    const int row  = blockIdx.x * 128 + lr;

    const float4* x4p = (const float4*)(in + (size_t)row * DIM);
    float x[64];
    #pragma unroll
    for (int i = 0; i < 16; ++i) {
        float4 v = x4p[i];
        x[4 * i + 0] = v.x; x[4 * i + 1] = v.y;
        x[4 * i + 2] = v.z; x[4 * i + 3] = v.w;
    }

    // A = ||x||^2, numpy pairwise 8-accumulator order, squares rounded separately
    float A;
    {
        #pragma clang fp contract(off)
        float racc[8];
        #pragma unroll
        for (int j = 0; j < 8; ++j) racc[j] = x[j] * x[j];
        #pragma unroll
        for (int t = 1; t < 8; ++t) {
            #pragma unroll
            for (int j = 0; j < 8; ++j) racc[j] += x[8 * t + j] * x[8 * t + j];
        }
        A = ((racc[0] + racc[1]) + (racc[2] + racc[3]))
          + ((racc[4] + racc[5]) + (racc[6] + racc[7]));
    }

    // Pin x in VGPRs: opaque defs, not rematerializable, cannot be re-loaded.
    #pragma unroll
    for (int j = 0; j < 64; ++j) asm volatile("" : "+v"(x[j]));

    // Force the split-k base into an SGPR so the codebook address is provably
    // wave-uniform -> s_load scalarization survives.
    const int    kbase = __builtin_amdgcn_readfirstlane(half << 9);
    const float* cbp   = cb  + ((size_t)kbase << 6);
    const float* cs    = csq + kbase;

    float dmin = 3.402823466e38f;
    int   kmin = 0;

    #pragma unroll 1
    for (int kk = 0; kk < 512; kk += 2) {
        const float* e0 = cbp + (kk << 6);
        const float* e1 = e0 + 64;
        // Sequential fma chains (same accumulation order as the passing R1
        // kernel); two independent chains hide dependent-fma latency.
        float m0 = 0.0f, m1 = 0.0f;
        #pragma unroll
        for (int j = 0; j < 64; ++j) {
            m0 = __builtin_fmaf(x[j], e0[j], m0);
            m1 = __builtin_fmaf(x[j], e1[j], m1);
        }
        float d0, d1;
        {
            #pragma clang fp contract(off)
            d0 = (A - 2.0f * m0) + cs[kk];
            d1 = (A - 2.0f * m1) + cs[kk + 1];
        }
        if (d0 < dmin) { dmin = d0; kmin = kk; }
        if (d1 < dmin) { dmin = d1; kmin = kk + 1; }
    }

    __shared__ float ds[256];
    __shared__ int   ks[256];
    ds[tid] = dmin;
    ks[tid] = kmin;
    __syncthreads();

    float lsum = 0.0f;
    if (tid < 128) {
        float d0 = ds[tid], d1 = ds[tid + 128];
        int   k0 = ks[tid], k1 = ks[tid + 128] + 512;
        // full-scan equivalence: second half wins only on strict <
        int   code = (d1 < d0) ? k1 : k0;
        float db   = (d1 < d0) ? d1 : d0;
        codes_f[row] = (float)code;
        lsum = db;
    }
    __syncthreads();
    ds[tid] = lsum;                 // threads >=128 contribute 0
    __syncthreads();
    #pragma unroll
    for (int s = 128; s > 0; s >>= 1) {
        if (tid < s) ds[tid] += ds[tid + s];
        __syncthreads();
    }
    if (tid == 0) atomicAdd(loss_acc, ds[0]);
}

// Coalesced gather + straight-through write; lane 0 of the grid also
// finalizes the loss (argmin kernel has fully completed by stream order).
__global__ __launch_bounds__(256) void vq_quant(const float* __restrict__ in,
                                                const float* __restrict__ cb,
                                                const float* __restrict__ codes_f,
                                                float* __restrict__ out,
                                                const float* __restrict__ loss_acc,
                                                float* __restrict__ loss_out) {
    int t = blockIdx.x * 256 + threadIdx.x;   // one float4 per thread
    int row = t >> 4;                          // 16 threads per row
    int seg = t & 15;
    int code = (int)codes_f[row];
    const float4* q4 = (const float4*)(cb + ((size_t)code << 6));
    float4 xv = ((const float4*)in)[t];
    float4 qv = q4[seg];
    float4 st;
    {
        #pragma clang fp contract(off)
        st.x = xv.x + (qv.x - xv.x);
        st.y = xv.y + (qv.y - xv.y);
        st.z = xv.z + (qv.z - xv.z);
        st.w = xv.w + (qv.w - xv.w);
    }
    ((float4*)out)[t] = st;
    if (t == 0) {
        // loss = codebook_loss + BETA*commitment = 1.25 * mean((x-q)^2)
        loss_out[0] = 1.25f * loss_acc[0] / 8388608.0f;
    }
}

extern "C" void kernel_launch(void* const* d_in, const int* in_sizes, int n_in,
                              void* d_out, int out_size, void* d_ws, size_t ws_size,
                              hipStream_t stream) {
    const float* in = (const float*)d_in[0];   // (32,4096,64) fp32
    const float* cb = (const float*)d_in[1];   // (1024,64)    fp32
    float* out     = (float*)d_out;
    float* codes_f = out + 8388608;
    float* loss_p  = out + 8519680;
    float* ws      = (float*)d_ws;

    vq_prep  <<<4,    256, 0, stream>>>(cb, ws);
    vq_argmin<<<1024, 256, 0, stream>>>(in, cb, ws + 256, codes_f, ws);
    vq_quant <<<8192, 256, 0, stream>>>(in, cb, codes_f, out, ws, loss_p);
}